// Round 10
// baseline (135.338 us; speedup 1.0000x reference)
//
#include <hip/hip_runtime.h>
#include <math.h>

// loss = -sum_ij d1[i,j] * log(d2[i,j] + 1e-5), fp32 in, scalar fp32 out.
//
// Session ledger (loss-kernel us):
//   R0 43.4 | R2 44.9 (VGPR pipe depth: null) | R3 37.7 (d1 sc0sc1nt)
//   R4/R8 31.0 (path split: d2 LDS-direct aux0, d1 VGPR bypass)
//   R5 39.6 (d2 aux19) | R6 34.0 (write-once 5blk/CU) | R7 39.7 (NT-only)
//   R9 29.3 (ds_read one stage ahead of slot reuse; lgkmcnt(1) guard) <- BEST
// Confirmed mechanisms:
//  - Two concurrent read-return paths: VGPR-return ~3.6 TB/s (R3, alone),
//    LDS-direct ~2.3 TB/s (R9). Non-default aux on the LDS stream loses
//    cache hits; d1 flags win only as full sc0 sc1 nt combo.
//  - Ring-4 @16KB (8 blk/CU, 32 waves/CU) > write-once @32KB (5 blk/CU).
//  - R9 removed the slot-reuse lgkm drain -> LDS path now at service rate.
//    Remaining imbalance: VGPR path finishes ~19 us, idles ~10 us.
//  - Reduction tree FROZEN (absmax 0.0): thread t owns t + p*STRIDE p=0..7,
//    per-component acc, CP applied strictly p=0..7, wave shuffle, 4-wave
//    LDS combine, partials[blk]. Load PATH does not affect values.
// R10: rebalance bytes across paths to match measured rates (61/39):
//      move d2 stages p6,p7 from the LDS path to the VGPR path (sc0sc1nt).
//      Per-thread: VGPR path 10x16B, LDS path 6x16B = 62.5/37.5.
//      16 VMEM ops/thread, full vmcnt bookkeeping below; CP order unchanged.

#define EPS 1e-5f
#define BLOCK 256
#define GRID 2048                 // GRID*BLOCK*8 == n4 exactly
#define STRIDE (GRID * BLOCK)     // float4 stride between a thread's windows

typedef float f4v __attribute__((ext_vector_type(4)));

#define AS1 __attribute__((address_space(1)))
#define AS3 __attribute__((address_space(3)))

// VGPR-return path load, L2-bypass + non-temporal (R3/R4 win).
#define LOADX(X, PA)                                                 \
    asm volatile("global_load_dwordx4 %0, %1, off sc0 sc1 nt"        \
                 : "=&v"(X) : "v"(PA) : "memory")

// Explicit LDS read: lgkm counting fully ours (DS ops retire in order).
#define DSR(Y, P)                                                    \
    asm volatile("ds_read_b128 %0, %1"                               \
                 : "=&v"(Y)                                          \
                 : "v"((unsigned)(size_t)(AS3 void*)&sB[P][threadIdx.x]) \
                 : "memory")

// Hand-counted vmem wait + scheduling fence (rule #18).
#define WAITV(N)                                              \
    do {                                                      \
        asm volatile("s_waitcnt vmcnt(" #N ")" ::: "memory"); \
        __builtin_amdgcn_sched_barrier(0);                    \
    } while (0)

// Hand-counted LDS wait + scheduling fence.
#define WAITL(N)                                                \
    do {                                                        \
        asm volatile("s_waitcnt lgkmcnt(" #N ")" ::: "memory"); \
        __builtin_amdgcn_sched_barrier(0);                      \
    } while (0)

// Same element->acc mapping and fma contraction as the baseline.
#define CP(X, Y)                                              \
    do {                                                      \
        acc0 = fmaf((X).x, __logf((Y).x + EPS), acc0);        \
        acc1 = fmaf((X).y, __logf((Y).y + EPS), acc1);        \
        acc2 = fmaf((X).z, __logf((Y).z + EPS), acc2);        \
        acc3 = fmaf((X).w, __logf((Y).w + EPS), acc3);        \
    } while (0)

__global__ __launch_bounds__(BLOCK) void cep_loss_kernel(
        const f4v* __restrict__ d1,
        const f4v* __restrict__ d2,
        float* __restrict__ partials) {
    // 4-deep ring: 4 x 256 x 16B = 16 KB/block -> 8 blocks/CU = 32 waves/CU.
    __shared__ f4v sB[4][BLOCK];

    const int tid = blockIdx.x * BLOCK + threadIdx.x;
    const int wb  = threadIdx.x & ~63;   // wave-uniform LDS slot base
    const f4v* pa = d1 + tid;
    const f4v* pb = d2 + tid;

    float acc0 = 0.0f, acc1 = 0.0f, acc2 = 0.0f, acc3 = 0.0f;
    f4v x0, x1, x2, x3, x4, x5, x6, x7;
    f4v y6, y7;
    f4v r0, r1, r2, r3, r4, r5;

    // Stage issue, LDS-path variant: d2 -> LDS-direct (DEFAULT policy,
    // cache-served); d1 -> VGPR path bypass. 2 vmcnt ops.
#define ISSUE(BUF, X)                                                    \
    do {                                                                 \
        __builtin_amdgcn_global_load_lds(                                \
            (const AS1 void*)pb, (AS3 void*)&sB[BUF][wb], 16, 0, 0);     \
        LOADX(X, pa);                                                    \
        pb += STRIDE; pa += STRIDE;                                      \
    } while (0)

    // Stage issue, VGPR-path variant (rebalanced stages p6,p7): both d2 and
    // d1 on the VGPR-return path with bypass policy. 2 vmcnt ops.
#define ISSUEV(Y, X)                                                     \
    do {                                                                 \
        LOADX(Y, pb);                                                    \
        LOADX(X, pa);                                                    \
        pb += STRIDE; pa += STRIDE;                                      \
    } while (0)

    // Prologue: stages p0..p3 via LDS path. ops1-8, vm out=8.
    ISSUE(0, x0); ISSUE(1, x1); ISSUE(2, x2); ISSUE(3, x3);

    // Read-ahead: slot reads issued one stage before reuse.
    WAITV(6); DSR(r0, 0);                 // ops1,2 done (s0,x0)
    WAITV(4); DSR(r1, 1);                 // ops3,4 done (s1,x1)

    // Steady state. vm-op bookkeeping in comments: [issued ops | outstanding]
    WAITL(1); ISSUE(0, x4); CP(x0, r0);   // ops9,10  | 5..10 = 6
    WAITV(4); DSR(r2, 2);                 // ops5,6 done (s2)   | 7..10 = 4
    WAITL(1); ISSUE(1, x5); CP(x1, r1);   // ops11,12 | 7..12 = 6
    WAITV(4); DSR(r3, 3);                 // ops7,8 done (s3)   | 9..12 = 4
    WAITL(1); ISSUEV(y6, x6); CP(x2, r2); // ops13,14 | 9..14 = 6 (p6 via VGPR)
    WAITV(4); DSR(r4, 0);                 // ops9,10 done (s0=p4, x4) | 11..14
    WAITL(1); ISSUEV(y7, x7); CP(x3, r3); // ops15,16 | 11..16 = 6 (p7 via VGPR)

    // Drain.
    WAITV(4); DSR(r5, 1);                 // ops11,12 done (s1=p5, x5) | 13..16
    WAITL(1); CP(x4, r4);
    WAITV(2);                             // ops13,14 done (y6, x6) | 15,16
    WAITL(0); CP(x5, r5);
    CP(x6, y6);
    WAITV(0); CP(x7, y7);                 // ops15,16 done

    float acc = (acc0 + acc1) + (acc2 + acc3);

    // Wave-64 shuffle reduction (identical tree to baseline).
    #pragma unroll
    for (int off = 32; off > 0; off >>= 1)
        acc += __shfl_down(acc, off, 64);

    __shared__ float wave_sums[BLOCK / 64];
    int lane = threadIdx.x & 63;
    int wid  = threadIdx.x >> 6;
    if (lane == 0) wave_sums[wid] = acc;
    __syncthreads();

    if (threadIdx.x == 0) {
        float s = wave_sums[0] + wave_sums[1] + wave_sums[2] + wave_sums[3];
        partials[blockIdx.x] = s;  // deterministic: no atomics
    }
}

__global__ __launch_bounds__(BLOCK) void cep_final_kernel(
        const float* __restrict__ partials, float* __restrict__ out, int nparts) {
    float acc = 0.0f;
    for (int i = threadIdx.x; i < nparts; i += BLOCK)
        acc += partials[i];

    #pragma unroll
    for (int off = 32; off > 0; off >>= 1)
        acc += __shfl_down(acc, off, 64);

    __shared__ float wave_sums[BLOCK / 64];
    int lane = threadIdx.x & 63;
    int wid  = threadIdx.x >> 6;
    if (lane == 0) wave_sums[wid] = acc;
    __syncthreads();

    if (threadIdx.x == 0) {
        float s = wave_sums[0] + wave_sums[1] + wave_sums[2] + wave_sums[3];
        out[0] = -s;
    }
}

extern "C" void kernel_launch(void* const* d_in, const int* in_sizes, int n_in,
                              void* d_out, int out_size, void* d_ws, size_t ws_size,
                              hipStream_t stream) {
    const f4v* d1 = (const f4v*)d_in[0];
    const f4v* d2 = (const f4v*)d_in[1];
    float* out      = (float*)d_out;
    float* partials = (float*)d_ws;

    // n = 4096*4096 floats -> n4 = 4,194,304 float4. GRID*BLOCK*8 == n4.
    cep_loss_kernel<<<GRID, BLOCK, 0, stream>>>(d1, d2, partials);
    cep_final_kernel<<<1, BLOCK, 0, stream>>>(partials, out, GRID);
}

// Round 11
// 134.103 us; speedup vs baseline: 1.0092x; 1.0092x over previous
//
#include <hip/hip_runtime.h>
#include <math.h>

// loss = -sum_ij d1[i,j] * log(d2[i,j] + 1e-5), fp32 in, scalar fp32 out.
//
// Session ledger (loss-kernel us):
//   R0 43.4 | R2 44.9 (VGPR pipe depth: null) | R3 37.7 (both-bypass VGPR)
//   R4/R8 31.0 (path split) | R5 39.6 (d2 aux19) | R6 34.0 (write-once)
//   R7 39.7 (NT-only) | R9 29.3 (read-ahead lgkm discipline)  <- BEST
//   R10 33.3 (rebalance 2 d2 stages to VGPR path WITH bypass: lost their
//             L3 hits - confounded policy+path, known-bad direction)
// Confirmed mechanisms:
//  - d2's bytes must keep default cache policy (R5/R7/R10: stripping cache
//    service from resident bytes costs +4..9 us every time).
//  - d1-bypass (sc0 sc1 nt) only wins as the full combo on the miss stream.
//  - Ring-4 @16KB (8 blk/CU) > write-once @32KB (5 blk/CU). Depth: null.
//  - R9: VGPR path ~3.6 TB/s, LDS-direct path ~2.3 TB/s straggler.
//  - Reduction tree FROZEN (absmax 0.0): thread t owns t + p*STRIDE p=0..7,
//    per-component acc, CP strictly p=0..7. Load path never affects values.
// R11: the UNCONFOUNDED rebalance - R10's exact schedule (verified absmax
//      0.0) with moved d2 stages p6,p7 on the VGPR-return path at DEFAULT
//      policy (keep their L3 hits). Isolates return-path choice at fixed
//      policy. Null => shared-service ceiling at ~4.6 TB/s => R9 is final.

#define EPS 1e-5f
#define BLOCK 256
#define GRID 2048                 // GRID*BLOCK*8 == n4 exactly
#define STRIDE (GRID * BLOCK)     // float4 stride between a thread's windows

typedef float f4v __attribute__((ext_vector_type(4)));

#define AS1 __attribute__((address_space(1)))
#define AS3 __attribute__((address_space(3)))

// VGPR-return path load, L2-bypass + non-temporal (d1 / miss stream only).
#define LOADX(X, PA)                                                 \
    asm volatile("global_load_dwordx4 %0, %1, off sc0 sc1 nt"        \
                 : "=&v"(X) : "v"(PA) : "memory")

// VGPR-return path load, DEFAULT policy (rebalanced d2 stages: keep hits).
#define LOADY(Y, PB)                                                 \
    asm volatile("global_load_dwordx4 %0, %1, off"                   \
                 : "=&v"(Y) : "v"(PB) : "memory")

// Explicit LDS read: lgkm counting fully ours (DS ops retire in order).
#define DSR(Y, P)                                                    \
    asm volatile("ds_read_b128 %0, %1"                               \
                 : "=&v"(Y)                                          \
                 : "v"((unsigned)(size_t)(AS3 void*)&sB[P][threadIdx.x]) \
                 : "memory")

// Hand-counted vmem wait + scheduling fence (rule #18).
#define WAITV(N)                                              \
    do {                                                      \
        asm volatile("s_waitcnt vmcnt(" #N ")" ::: "memory"); \
        __builtin_amdgcn_sched_barrier(0);                    \
    } while (0)

// Hand-counted LDS wait + scheduling fence.
#define WAITL(N)                                                \
    do {                                                        \
        asm volatile("s_waitcnt lgkmcnt(" #N ")" ::: "memory"); \
        __builtin_amdgcn_sched_barrier(0);                      \
    } while (0)

// Same element->acc mapping and fma contraction as the baseline.
#define CP(X, Y)                                              \
    do {                                                      \
        acc0 = fmaf((X).x, __logf((Y).x + EPS), acc0);        \
        acc1 = fmaf((X).y, __logf((Y).y + EPS), acc1);        \
        acc2 = fmaf((X).z, __logf((Y).z + EPS), acc2);        \
        acc3 = fmaf((X).w, __logf((Y).w + EPS), acc3);        \
    } while (0)

__global__ __launch_bounds__(BLOCK) void cep_loss_kernel(
        const f4v* __restrict__ d1,
        const f4v* __restrict__ d2,
        float* __restrict__ partials) {
    // 4-deep ring: 4 x 256 x 16B = 16 KB/block -> 8 blocks/CU = 32 waves/CU.
    __shared__ f4v sB[4][BLOCK];

    const int tid = blockIdx.x * BLOCK + threadIdx.x;
    const int wb  = threadIdx.x & ~63;   // wave-uniform LDS slot base
    const f4v* pa = d1 + tid;
    const f4v* pb = d2 + tid;

    float acc0 = 0.0f, acc1 = 0.0f, acc2 = 0.0f, acc3 = 0.0f;
    f4v x0, x1, x2, x3, x4, x5, x6, x7;
    f4v y6, y7;
    f4v r0, r1, r2, r3, r4, r5;

    // Stage issue, LDS-path variant: d2 -> LDS-direct (DEFAULT policy,
    // cache-served); d1 -> VGPR path bypass. 2 vmcnt ops.
#define ISSUE(BUF, X)                                                    \
    do {                                                                 \
        __builtin_amdgcn_global_load_lds(                                \
            (const AS1 void*)pb, (AS3 void*)&sB[BUF][wb], 16, 0, 0);     \
        LOADX(X, pa);                                                    \
        pb += STRIDE; pa += STRIDE;                                      \
    } while (0)

    // Stage issue, VGPR-path variant (rebalanced stages p6,p7): d2 on the
    // VGPR-return path at DEFAULT policy; d1 bypass. 2 vmcnt ops.
#define ISSUEV(Y, X)                                                     \
    do {                                                                 \
        LOADY(Y, pb);                                                    \
        LOADX(X, pa);                                                    \
        pb += STRIDE; pa += STRIDE;                                      \
    } while (0)

    // Prologue: stages p0..p3 via LDS path. ops1-8, vm out=8.
    ISSUE(0, x0); ISSUE(1, x1); ISSUE(2, x2); ISSUE(3, x3);

    // Read-ahead: slot reads issued one stage before reuse.
    WAITV(6); DSR(r0, 0);                 // ops1,2 done (s0,x0)
    WAITV(4); DSR(r1, 1);                 // ops3,4 done (s1,x1)

    // Steady state. vm-op bookkeeping: [issued ops | outstanding]
    WAITL(1); ISSUE(0, x4); CP(x0, r0);   // ops9,10  | 5..10 = 6
    WAITV(4); DSR(r2, 2);                 // ops5,6 done (s2)   | 7..10 = 4
    WAITL(1); ISSUE(1, x5); CP(x1, r1);   // ops11,12 | 7..12 = 6
    WAITV(4); DSR(r3, 3);                 // ops7,8 done (s3)   | 9..12 = 4
    WAITL(1); ISSUEV(y6, x6); CP(x2, r2); // ops13,14 | 9..14 = 6 (p6 via VGPR)
    WAITV(4); DSR(r4, 0);                 // ops9,10 done (s0=p4, x4) | 11..14
    WAITL(1); ISSUEV(y7, x7); CP(x3, r3); // ops15,16 | 11..16 = 6 (p7 via VGPR)

    // Drain.
    WAITV(4); DSR(r5, 1);                 // ops11,12 done (s1=p5, x5) | 13..16
    WAITL(1); CP(x4, r4);
    WAITV(2);                             // ops13,14 done (y6, x6) | 15,16
    WAITL(0); CP(x5, r5);
    CP(x6, y6);
    WAITV(0); CP(x7, y7);                 // ops15,16 done

    float acc = (acc0 + acc1) + (acc2 + acc3);

    // Wave-64 shuffle reduction (identical tree to baseline).
    #pragma unroll
    for (int off = 32; off > 0; off >>= 1)
        acc += __shfl_down(acc, off, 64);

    __shared__ float wave_sums[BLOCK / 64];
    int lane = threadIdx.x & 63;
    int wid  = threadIdx.x >> 6;
    if (lane == 0) wave_sums[wid] = acc;
    __syncthreads();

    if (threadIdx.x == 0) {
        float s = wave_sums[0] + wave_sums[1] + wave_sums[2] + wave_sums[3];
        partials[blockIdx.x] = s;  // deterministic: no atomics
    }
}

__global__ __launch_bounds__(BLOCK) void cep_final_kernel(
        const float* __restrict__ partials, float* __restrict__ out, int nparts) {
    float acc = 0.0f;
    for (int i = threadIdx.x; i < nparts; i += BLOCK)
        acc += partials[i];

    #pragma unroll
    for (int off = 32; off > 0; off >>= 1)
        acc += __shfl_down(acc, off, 64);

    __shared__ float wave_sums[BLOCK / 64];
    int lane = threadIdx.x & 63;
    int wid  = threadIdx.x >> 6;
    if (lane == 0) wave_sums[wid] = acc;
    __syncthreads();

    if (threadIdx.x == 0) {
        float s = wave_sums[0] + wave_sums[1] + wave_sums[2] + wave_sums[3];
        out[0] = -s;
    }
}

extern "C" void kernel_launch(void* const* d_in, const int* in_sizes, int n_in,
                              void* d_out, int out_size, void* d_ws, size_t ws_size,
                              hipStream_t stream) {
    const f4v* d1 = (const f4v*)d_in[0];
    const f4v* d2 = (const f4v*)d_in[1];
    float* out      = (float*)d_out;
    float* partials = (float*)d_ws;

    // n = 4096*4096 floats -> n4 = 4,194,304 float4. GRID*BLOCK*8 == n4.
    cep_loss_kernel<<<GRID, BLOCK, 0, stream>>>(d1, d2, partials);
    cep_final_kernel<<<1, BLOCK, 0, stream>>>(partials, out, GRID);
}

// Round 12
// 131.538 us; speedup vs baseline: 1.0289x; 1.0195x over previous
//
#include <hip/hip_runtime.h>
#include <math.h>

// loss = -sum_ij d1[i,j] * log(d2[i,j] + 1e-5), fp32 in, scalar fp32 out.
//
// FINAL CONFIGURATION (R9 restoration). Session ledger (loss-kernel us):
//   R0 43.4 | R2 44.9 (VGPR pipe depth: null) | R3 37.7 (both-bypass VGPR)
//   R4/R8 31.0 (path split) | R5 39.6 (d2 aux19) | R6 34.0 (write-once)
//   R7 39.7 (NT-only) | R9 29.3 <- BEST | R10 33.3 (rebalance w/ bypass)
//   R11 32.1 (rebalance w/ default policy)
// R9 is a measured local optimum on EVERY axis:
//  - d1 policy: full sc0 sc1 nt combo only (R3 win, R7 nt-only loss).
//  - d2 policy: default only (R5 aux19, R7 aux2, R10 bypass: all lose
//    the ~50% dirty-L3 hits, +4..9 us each).
//  - Path split: d2 via global_load_lds (TA->LDS return), d1 via VGPR
//    return (R4: -18%). Rebalancing bytes across paths loses either way
//    (R10/R11) - joint service limit ~4.6 TB/s for this mixed pattern.
//  - Depth: null (R2, R6). Occupancy: ring-4 @16KB -> 8 blk/CU (R6).
//  - lgkm: ds_read one stage ahead of slot reuse, lgkmcnt(1) guard (R9).
//  - Fusion: agent-scope fences cost more than the saved dispatch (R1).
// Ceiling: 134 MB / 29.3 us = 4.6 TB/s aggregate via two concurrent
// return paths (~3.6 VGPR + ~2.3 LDS-direct); single-direction fill
// ceiling is 6.6 TB/s but the mixed dirty-L3/HBM read pattern binds lower.
// Reduction tree FROZEN (absmax 0.0): thread t owns t + p*STRIDE p=0..7,
// per-component acc, CP strictly p=0..7, wave shuffle, 4-wave LDS
// combine, partials[blk], 1-block final reduce.

#define EPS 1e-5f
#define BLOCK 256
#define GRID 2048                 // GRID*BLOCK*8 == n4 exactly
#define STRIDE (GRID * BLOCK)     // float4 stride between a thread's windows

typedef float f4v __attribute__((ext_vector_type(4)));

#define AS1 __attribute__((address_space(1)))
#define AS3 __attribute__((address_space(3)))

// d1 load on the VGPR-return path, L2-bypass + non-temporal (R3/R4 win).
#define LOADX(X, PA)                                                 \
    asm volatile("global_load_dwordx4 %0, %1, off sc0 sc1 nt"        \
                 : "=&v"(X) : "v"(PA) : "memory")

// Explicit LDS read: lgkm counting fully ours (DS ops retire in order).
#define DSR(Y, P)                                                    \
    asm volatile("ds_read_b128 %0, %1"                               \
                 : "=&v"(Y)                                          \
                 : "v"((unsigned)(size_t)(AS3 void*)&sB[P][threadIdx.x]) \
                 : "memory")

// Hand-counted vmem wait + scheduling fence (rule #18).
#define WAITV(N)                                              \
    do {                                                      \
        asm volatile("s_waitcnt vmcnt(" #N ")" ::: "memory"); \
        __builtin_amdgcn_sched_barrier(0);                    \
    } while (0)

// Hand-counted LDS wait + scheduling fence.
#define WAITL(N)                                                \
    do {                                                        \
        asm volatile("s_waitcnt lgkmcnt(" #N ")" ::: "memory"); \
        __builtin_amdgcn_sched_barrier(0);                      \
    } while (0)

// Same element->acc mapping and fma contraction as the baseline.
#define CP(X, Y)                                              \
    do {                                                      \
        acc0 = fmaf((X).x, __logf((Y).x + EPS), acc0);        \
        acc1 = fmaf((X).y, __logf((Y).y + EPS), acc1);        \
        acc2 = fmaf((X).z, __logf((Y).z + EPS), acc2);        \
        acc3 = fmaf((X).w, __logf((Y).w + EPS), acc3);        \
    } while (0)

__global__ __launch_bounds__(BLOCK) void cep_loss_kernel(
        const f4v* __restrict__ d1,
        const f4v* __restrict__ d2,
        float* __restrict__ partials) {
    // 4-deep ring: 4 x 256 x 16B = 16 KB/block -> 8 blocks/CU = 32 waves/CU.
    __shared__ f4v sB[4][BLOCK];

    const int tid = blockIdx.x * BLOCK + threadIdx.x;
    const int wb  = threadIdx.x & ~63;   // wave-uniform LDS slot base
    const f4v* pa = d1 + tid;
    const f4v* pb = d2 + tid;

    float acc0 = 0.0f, acc1 = 0.0f, acc2 = 0.0f, acc3 = 0.0f;
    f4v x0, x1, x2, x3, x4, x5, x6, x7;
    f4v r0, r1, r2, r3, r4, r5, r6, r7;

    // One stage: d2 -> LDS-direct DEFAULT policy (cache-served);
    // d1 -> VGPR path sc0 sc1 nt (HBM-direct). 2 vmcnt ops/stage.
#define ISSUE(BUF, X)                                                    \
    do {                                                                 \
        __builtin_amdgcn_global_load_lds(                                \
            (const AS1 void*)pb, (AS3 void*)&sB[BUF][wb], 16, 0, 0);     \
        LOADX(X, pa);                                                    \
        pb += STRIDE; pa += STRIDE;                                      \
    } while (0)

    // Prologue: 4 stages in flight (vmcnt = 8).
    ISSUE(0, x0); ISSUE(1, x1); ISSUE(2, x2); ISSUE(3, x3);

    // Read-ahead prologue: slot0 and slot1 ds_reads issued before any reuse.
    WAITV(6); DSR(r0, 0);                       // lgkm: {r0}
    WAITV(4); DSR(r1, 1);                       // lgkm: {r0,r1}
    // Steady state: guard slot reuse with lgkmcnt(1) on a read issued a
    // full stage earlier (in-order DS retire => oldest is done). Keep
    // reading one slot ahead of the reissue.
    WAITL(1); ISSUE(0, x4); CP(x0, r0);         // slot0 reused; r1 pending
    WAITV(4); DSR(r2, 2);
    WAITL(1); ISSUE(1, x5); CP(x1, r1);
    WAITV(4); DSR(r3, 3);
    WAITL(1); ISSUE(2, x6); CP(x2, r2);
    WAITV(4); DSR(r4, 0);                       // slot0, second generation
    WAITL(1); ISSUE(3, x7); CP(x3, r3);
    // Drain: no more reissues, just read-ahead + compute.
    WAITV(4); DSR(r5, 1);
    WAITL(1); CP(x4, r4);
    WAITV(2); DSR(r6, 2);
    WAITL(1); CP(x5, r5);
    WAITV(0); DSR(r7, 3);
    WAITL(1); CP(x6, r6);
    WAITL(0); CP(x7, r7);

    float acc = (acc0 + acc1) + (acc2 + acc3);

    // Wave-64 shuffle reduction (identical tree to baseline).
    #pragma unroll
    for (int off = 32; off > 0; off >>= 1)
        acc += __shfl_down(acc, off, 64);

    __shared__ float wave_sums[BLOCK / 64];
    int lane = threadIdx.x & 63;
    int wid  = threadIdx.x >> 6;
    if (lane == 0) wave_sums[wid] = acc;
    __syncthreads();

    if (threadIdx.x == 0) {
        float s = wave_sums[0] + wave_sums[1] + wave_sums[2] + wave_sums[3];
        partials[blockIdx.x] = s;  // deterministic: no atomics
    }
}

__global__ __launch_bounds__(BLOCK) void cep_final_kernel(
        const float* __restrict__ partials, float* __restrict__ out, int nparts) {
    float acc = 0.0f;
    for (int i = threadIdx.x; i < nparts; i += BLOCK)
        acc += partials[i];

    #pragma unroll
    for (int off = 32; off > 0; off >>= 1)
        acc += __shfl_down(acc, off, 64);

    __shared__ float wave_sums[BLOCK / 64];
    int lane = threadIdx.x & 63;
    int wid  = threadIdx.x >> 6;
    if (lane == 0) wave_sums[wid] = acc;
    __syncthreads();

    if (threadIdx.x == 0) {
        float s = wave_sums[0] + wave_sums[1] + wave_sums[2] + wave_sums[3];
        out[0] = -s;
    }
}

extern "C" void kernel_launch(void* const* d_in, const int* in_sizes, int n_in,
                              void* d_out, int out_size, void* d_ws, size_t ws_size,
                              hipStream_t stream) {
    const f4v* d1 = (const f4v*)d_in[0];
    const f4v* d2 = (const f4v*)d_in[1];
    float* out      = (float*)d_out;
    float* partials = (float*)d_ws;

    // n = 4096*4096 floats -> n4 = 4,194,304 float4. GRID*BLOCK*8 == n4.
    cep_loss_kernel<<<GRID, BLOCK, 0, stream>>>(d1, d2, partials);
    cep_final_kernel<<<1, BLOCK, 0, stream>>>(partials, out, GRID);
}